// Round 6
// baseline (390.792 us; speedup 1.0000x reference)
//
#include <hip/hip_runtime.h>

#define NN 100000
#define DD 256
#define SCAN_BLK 1024

typedef unsigned int uint;
typedef unsigned short ushort;
typedef __attribute__((ext_vector_type(8))) short bfx8;
typedef __attribute__((ext_vector_type(4))) float fx4;

__device__ __forceinline__ ushort f2bf(float f) {  // RNE
    uint u = __float_as_uint(f);
    u += 0x7fff + ((u >> 16) & 1);
    return (ushort)(u >> 16);
}

// ---------------- degree / norm ----------------
__global__ __launch_bounds__(256) void k_init_deg(int* __restrict__ dego,
                                                  int* __restrict__ degi) {
    int i = blockIdx.x * 256 + threadIdx.x;
    if (i < NN) { dego[i] = 1; degi[i] = 1; }  // self-loop contributes 1
}

__global__ __launch_bounds__(256) void k_count(const int* __restrict__ src,
                                               const int* __restrict__ dst, int E,
                                               int* __restrict__ dego,
                                               int* __restrict__ degi) {
    int e = blockIdx.x * 256 + threadIdx.x;
    if (e < E) {
        atomicAdd(&dego[src[e]], 1);
        atomicAdd(&degi[dst[e]], 1);
    }
}

__global__ __launch_bounds__(256) void k_norm(const int* __restrict__ dego,
                                              const int* __restrict__ degi,
                                              float* __restrict__ ns,
                                              float* __restrict__ nd) {
    int i = blockIdx.x * 256 + threadIdx.x;
    if (i < NN) {
        ns[i] = rsqrtf((float)dego[i]);
        nd[i] = rsqrtf((float)degi[i]);
    }
}

// ---------------- CSR build (scan by dst) ----------------
__device__ __forceinline__ int block_scan_inc(int v, int* sm) {
    int t = threadIdx.x;
    sm[t] = v;
    __syncthreads();
    for (int o = 1; o < SCAN_BLK; o <<= 1) {
        int x = (t >= o) ? sm[t - o] : 0;
        __syncthreads();
        sm[t] += x;
        __syncthreads();
    }
    return sm[t];
}

__global__ __launch_bounds__(SCAN_BLK) void k_scan1(const int* __restrict__ degi,
                                                    int* __restrict__ partials) {
    __shared__ int sm[SCAN_BLK];
    int i = blockIdx.x * SCAN_BLK + threadIdx.x;
    int v = (i < NN) ? (degi[i] - 1) : 0;  // real in-edges only
    block_scan_inc(v, sm);
    if (threadIdx.x == 0) partials[blockIdx.x] = sm[SCAN_BLK - 1];
}

__global__ __launch_bounds__(128) void k_scan2(int* __restrict__ partials, int nb) {
    __shared__ int sm[128];
    int t = threadIdx.x;
    int v = (t < nb) ? partials[t] : 0;
    sm[t] = v;
    __syncthreads();
    for (int o = 1; o < 128; o <<= 1) {
        int x = (t >= o) ? sm[t - o] : 0;
        __syncthreads();
        sm[t] += x;
        __syncthreads();
    }
    if (t < nb) partials[t] = sm[t] - v;  // exclusive
}

__global__ __launch_bounds__(SCAN_BLK) void k_scan3(const int* __restrict__ degi,
                                                    const int* __restrict__ partials,
                                                    int* __restrict__ rowptr,
                                                    int* __restrict__ cursor) {
    __shared__ int sm[SCAN_BLK];
    int i = blockIdx.x * SCAN_BLK + threadIdx.x;
    int v = (i < NN) ? (degi[i] - 1) : 0;
    int incl = block_scan_inc(v, sm);
    int excl = partials[blockIdx.x] + incl - v;
    if (i <= NN) rowptr[i] = excl;   // rowptr[NN] = E
    if (i < NN) cursor[i] = excl;
}

__global__ __launch_bounds__(256) void k_fill(const int* __restrict__ src,
                                              const int* __restrict__ dst, int E,
                                              int* __restrict__ cursor,
                                              int* __restrict__ eidx) {
    int e = blockIdx.x * 256 + threadIdx.x;
    if (e < E) {
        int d = dst[e];
        int p = atomicAdd(&cursor[d], 1);
        eidx[p] = src[e];
    }
}

// Wt[n][k] = bf16(W[k][n])  (transposed so GEMM B-frags read k-contiguous)
__global__ __launch_bounds__(256) void k_convW(const float* __restrict__ W,
                                               ushort* __restrict__ Wt) {
    int n = blockIdx.x, k = threadIdx.x;
    Wt[n * DD + k] = f2bf(W[(size_t)k * DD + n]);
}

// ---------------- MFMA GEMM: H = A @ Wt^T, single column pass ----------------
// Tile 128x256 (BN = full D -> A read exactly ONCE), BK=64, 512 threads
// (8 waves, 2x4 grid), wave tile 64x64 (4x4 frags of 16x16x32). Both A chunk
// (16 KB) and Wt chunk (32 KB) double-buffered: 96 KB LDS. Wt (128 KB total)
// is L2-resident per XCD, so the per-block re-read is ~free on the fabric.
// XOR-swizzled 16B chunks (same verified scheme as rounds 3-5). FP32A=true
// reads fp32 A and applies per-row scale nrm while converting to bf16.
template <bool FP32A>
__global__ __launch_bounds__(512) void k_mfgemm(const void* __restrict__ Av,
                                                const float* __restrict__ nrm,
                                                const ushort* __restrict__ Wt,
                                                ushort* __restrict__ H) {
    __shared__ uint4 atq[2][128 * 8];  // A tile [128 r][8 chunks], dbuf
    __shared__ uint4 wtq[2][256 * 8];  // Wt chunk [256 n][8 chunks], dbuf
    int t = threadIdx.x;
    int brow = blockIdx.x * 128;
    int lane = t & 63, w = t >> 6;
    int wr = w >> 2, wc = w & 3;       // wave grid 2x4
    int lg = lane >> 4, lr = lane & 15;

    int sr = t >> 3, sc = t & 7;       // staging: row/n = sr (+i*64), chunk sc

    int rows_[2];
    float ns_[2];
#pragma unroll
    for (int i = 0; i < 2; ++i) {
        int r = brow + sr + i * 64;
        if (r >= NN) r = NN - 1;  // tail clamp (results discarded on store)
        rows_[i] = r;
        if (FP32A) ns_[i] = nrm[r];
    }

    fx4 acc[4][4];
#pragma unroll
    for (int mi = 0; mi < 4; ++mi)
#pragma unroll
        for (int ni = 0; ni < 4; ++ni)
            acc[mi][ni] = (fx4){0.f, 0.f, 0.f, 0.f};

    uint4 sva[2];        // A staging regs (bf16 path)
    float4 svf[2][2];    // A staging regs (fp32 path)
    uint4 svw[4];        // Wt staging regs

    auto ldA = [&](int ks) {
        if (FP32A) {
            const float* X = (const float*)Av;
#pragma unroll
            for (int i = 0; i < 2; ++i) {
                const float4* p =
                    (const float4*)(X + (size_t)rows_[i] * DD + ks * 64 + sc * 8);
                svf[i][0] = p[0];
                svf[i][1] = p[1];
            }
        } else {
            const ushort* A = (const ushort*)Av;
#pragma unroll
            for (int i = 0; i < 2; ++i)
                sva[i] = *(const uint4*)(A + (size_t)rows_[i] * DD + ks * 64 + sc * 8);
        }
    };
    auto ldW = [&](int ks) {
        const uint4* Wq = (const uint4*)Wt;
#pragma unroll
        for (int i = 0; i < 4; ++i) {
            int n = sr + i * 64;
            svw[i] = Wq[(size_t)n * 32 + ks * 8 + sc];
        }
    };
    auto wrA = [&](int buf) {
#pragma unroll
        for (int i = 0; i < 2; ++i) {
            int r = sr + i * 64;
            uint4 u;
            if (FP32A) {
                float s = ns_[i];
                float4 a = svf[i][0], b = svf[i][1];
                u.x = (uint)f2bf(a.x * s) | ((uint)f2bf(a.y * s) << 16);
                u.y = (uint)f2bf(a.z * s) | ((uint)f2bf(a.w * s) << 16);
                u.z = (uint)f2bf(b.x * s) | ((uint)f2bf(b.y * s) << 16);
                u.w = (uint)f2bf(b.z * s) | ((uint)f2bf(b.w * s) << 16);
            } else {
                u = sva[i];
            }
            atq[buf][r * 8 + (sc ^ (r & 7))] = u;
        }
    };
    auto wrW = [&](int buf) {
#pragma unroll
        for (int i = 0; i < 4; ++i) {
            int n = sr + i * 64;
            wtq[buf][n * 8 + (sc ^ (n & 7))] = svw[i];
        }
    };

    ldA(0);
    ldW(0);
    wrA(0);
    wrW(0);
    __syncthreads();

    int buf = 0;
    for (int ks = 0; ks < 4; ++ks) {
        if (ks < 3) { ldA(ks + 1); ldW(ks + 1); }  // issue early: hide under MFMA
#pragma unroll
        for (int kk = 0; kk < 2; ++kk) {
            bfx8 af[4], bfr[4];
#pragma unroll
            for (int mi = 0; mi < 4; ++mi) {
                int r = wr * 64 + mi * 16 + lr;
                int c = kk * 4 + lg;
                af[mi] = *(const bfx8*)&atq[buf][r * 8 + (c ^ (r & 7))];
            }
#pragma unroll
            for (int ni = 0; ni < 4; ++ni) {
                int n = wc * 64 + ni * 16 + lr;
                int c2 = kk * 4 + lg;
                bfr[ni] = *(const bfx8*)&wtq[buf][n * 8 + (c2 ^ (n & 7))];
            }
#pragma unroll
            for (int mi = 0; mi < 4; ++mi)
#pragma unroll
                for (int ni = 0; ni < 4; ++ni)
                    acc[mi][ni] = __builtin_amdgcn_mfma_f32_16x16x32_bf16(
                        af[mi], bfr[ni], acc[mi][ni], 0, 0, 0);
        }
        if (ks < 3) { wrA(buf ^ 1); wrW(buf ^ 1); }  // write late, other buffer
        __syncthreads();
        buf ^= 1;
    }

    // epilogue: C/D layout col=lane&15, row=(lane>>4)*4+reg (verified m89/m91)
#pragma unroll
    for (int mi = 0; mi < 4; ++mi) {
        int rbase = brow + wr * 64 + mi * 16 + lg * 4;
#pragma unroll
        for (int ni = 0; ni < 4; ++ni) {
            int col = wc * 64 + ni * 16 + lr;
#pragma unroll
            for (int j = 0; j < 4; ++j) {
                int row = rbase + j;
                if (row < NN) H[(size_t)row * DD + col] = f2bf(acc[mi][ni][j]);
            }
        }
    }
}

// ---------------- SpMM (bf16 gather, fp32 accum): one wave per dst node ----
// layer1: obf = bf16(relu(agg*nd + b) * ns)   (pre-scaled next-GEMM input)
// layer2: of  = agg*nd + b (final fp32, nontemporal store: write-once data,
//               keep it from evicting the gather working set)
__global__ __launch_bounds__(256) void k_spmm_bf(const ushort* __restrict__ T,
                                                 const int* __restrict__ rowptr,
                                                 const int* __restrict__ eidx,
                                                 const float* __restrict__ nd,
                                                 const float* __restrict__ ns,
                                                 const float* __restrict__ bias,
                                                 ushort* __restrict__ obf,
                                                 float* __restrict__ of,
                                                 int layer1) {
    int wid = threadIdx.x >> 6, lane = threadIdx.x & 63;
    int node = blockIdx.x * 4 + wid;
    if (node >= NN) return;
    int c = lane << 2;  // 4 bf16 per lane
    uint2 sv = *(const uint2*)(T + (size_t)node * DD + c);  // self-loop
    float p0[4], p1[4], p2[4], p3[4];
    p0[0] = __uint_as_float(sv.x << 16);
    p0[1] = __uint_as_float(sv.x & 0xffff0000u);
    p0[2] = __uint_as_float(sv.y << 16);
    p0[3] = __uint_as_float(sv.y & 0xffff0000u);
#pragma unroll
    for (int j = 0; j < 4; ++j) { p1[j] = 0.f; p2[j] = 0.f; p3[j] = 0.f; }
    int e = rowptr[node], end = rowptr[node + 1];
    for (; e + 3 < end; e += 4) {
        int s0 = eidx[e], s1 = eidx[e + 1], s2 = eidx[e + 2], s3 = eidx[e + 3];
        uint2 v0 = *(const uint2*)(T + (size_t)s0 * DD + c);
        uint2 v1 = *(const uint2*)(T + (size_t)s1 * DD + c);
        uint2 v2 = *(const uint2*)(T + (size_t)s2 * DD + c);
        uint2 v3 = *(const uint2*)(T + (size_t)s3 * DD + c);
        p0[0] += __uint_as_float(v0.x << 16);
        p0[1] += __uint_as_float(v0.x & 0xffff0000u);
        p0[2] += __uint_as_float(v0.y << 16);
        p0[3] += __uint_as_float(v0.y & 0xffff0000u);
        p1[0] += __uint_as_float(v1.x << 16);
        p1[1] += __uint_as_float(v1.x & 0xffff0000u);
        p1[2] += __uint_as_float(v1.y << 16);
        p1[3] += __uint_as_float(v1.y & 0xffff0000u);
        p2[0] += __uint_as_float(v2.x << 16);
        p2[1] += __uint_as_float(v2.x & 0xffff0000u);
        p2[2] += __uint_as_float(v2.y << 16);
        p2[3] += __uint_as_float(v2.y & 0xffff0000u);
        p3[0] += __uint_as_float(v3.x << 16);
        p3[1] += __uint_as_float(v3.x & 0xffff0000u);
        p3[2] += __uint_as_float(v3.y << 16);
        p3[3] += __uint_as_float(v3.y & 0xffff0000u);
    }
    for (; e < end; ++e) {
        int s0 = eidx[e];
        uint2 v0 = *(const uint2*)(T + (size_t)s0 * DD + c);
        p0[0] += __uint_as_float(v0.x << 16);
        p0[1] += __uint_as_float(v0.x & 0xffff0000u);
        p0[2] += __uint_as_float(v0.y << 16);
        p0[3] += __uint_as_float(v0.y & 0xffff0000u);
    }
#pragma unroll
    for (int j = 0; j < 4; ++j) p0[j] += (p1[j] + p2[j]) + p3[j];
    float n = nd[node];
    float4 bb = *(const float4*)(bias + c);
    float o0 = fmaf(p0[0], n, bb.x);
    float o1 = fmaf(p0[1], n, bb.y);
    float o2 = fmaf(p0[2], n, bb.z);
    float o3 = fmaf(p0[3], n, bb.w);
    if (layer1) {
        float s = ns[node];
        o0 = fmaxf(o0, 0.f) * s; o1 = fmaxf(o1, 0.f) * s;
        o2 = fmaxf(o2, 0.f) * s; o3 = fmaxf(o3, 0.f) * s;
        uint lo = (uint)f2bf(o0) | ((uint)f2bf(o1) << 16);
        uint hi = (uint)f2bf(o2) | ((uint)f2bf(o3) << 16);
        *(uint2*)(obf + (size_t)node * DD + c) = make_uint2(lo, hi);
    } else {
        fx4 o = {o0, o1, o2, o3};
        __builtin_nontemporal_store(o, (fx4*)(of + (size_t)node * DD + c));
    }
}

extern "C" void kernel_launch(void* const* d_in, const int* in_sizes, int n_in,
                              void* d_out, int out_size, void* d_ws, size_t ws_size,
                              hipStream_t stream) {
    const float* features = (const float*)d_in[0];
    const int* src = (const int*)d_in[1];
    const int* dst = (const int*)d_in[2];
    const float* W1 = (const float*)d_in[3];
    const float* b1 = (const float*)d_in[4];
    const float* W2 = (const float*)d_in[5];
    const float* b2 = (const float*)d_in[6];
    int E = in_sizes[1];
    float* out = (float*)d_out;

    size_t off = 0;
    auto alloc = [&](size_t nbytes) -> void* {
        void* p = (char*)d_ws + off;
        off += (nbytes + 255) & ~(size_t)255;
        return p;
    };
    int* dego = (int*)alloc((size_t)NN * 4);
    int* degi = (int*)alloc((size_t)NN * 4);
    float* norm_src = (float*)alloc((size_t)NN * 4);
    float* norm_dst = (float*)alloc((size_t)NN * 4);
    int* rowptr = (int*)alloc((size_t)(NN + 1) * 4);
    int* cursor = (int*)alloc((size_t)NN * 4);
    int* partials = (int*)alloc(128 * 4);
    int* eidx = (int*)alloc((size_t)E * 4);
    ushort* Wt1 = (ushort*)alloc((size_t)DD * DD * 2);
    ushort* Wt2 = (ushort*)alloc((size_t)DD * DD * 2);
    ushort* Xbf = (ushort*)alloc((size_t)NN * DD * 2);
    ushort* Hbf = (ushort*)alloc((size_t)NN * DD * 2);

    const int NB = (NN + SCAN_BLK - 1) / SCAN_BLK;  // 98

    k_init_deg<<<(NN + 255) / 256, 256, 0, stream>>>(dego, degi);
    k_count<<<(E + 255) / 256, 256, 0, stream>>>(src, dst, E, dego, degi);
    k_norm<<<(NN + 255) / 256, 256, 0, stream>>>(dego, degi, norm_src, norm_dst);
    k_scan1<<<NB, SCAN_BLK, 0, stream>>>(degi, partials);
    k_scan2<<<1, 128, 0, stream>>>(partials, NB);
    k_scan3<<<NB, SCAN_BLK, 0, stream>>>(degi, partials, rowptr, cursor);
    k_fill<<<(E + 255) / 256, 256, 0, stream>>>(src, dst, E, cursor, eidx);

    k_convW<<<DD, DD, 0, stream>>>(W1, Wt1);
    k_convW<<<DD, DD, 0, stream>>>(W2, Wt2);

    dim3 ggrid((NN + 127) / 128);  // 782, single column pass (BN=256)
    // layer 1 (GEMM reads fp32 features, scales by norm_src while staging)
    k_mfgemm<true><<<ggrid, 512, 0, stream>>>(features, norm_src, Wt1, Hbf);
    k_spmm_bf<<<(NN + 3) / 4, 256, 0, stream>>>(Hbf, rowptr, eidx, norm_dst,
                                                norm_src, b1, Xbf, out, 1);
    // layer 2
    k_mfgemm<false><<<ggrid, 512, 0, stream>>>(Xbf, nullptr, Wt2, Hbf);
    k_spmm_bf<<<(NN + 3) / 4, 256, 0, stream>>>(Hbf, rowptr, eidx, norm_dst,
                                                norm_src, b2, nullptr, out, 0);
}

// Round 7
// 384.878 us; speedup vs baseline: 1.0154x; 1.0154x over previous
//
#include <hip/hip_runtime.h>

#define NN 100000
#define DD 256
#define SCAN_BLK 1024

typedef unsigned int uint;
typedef unsigned short ushort;
typedef __attribute__((ext_vector_type(8))) short bfx8;
typedef __attribute__((ext_vector_type(4))) float fx4;

__device__ __forceinline__ ushort f2bf(float f) {  // RNE
    uint u = __float_as_uint(f);
    u += 0x7fff + ((u >> 16) & 1);
    return (ushort)(u >> 16);
}

// ---------------- degree / norm ----------------
__global__ __launch_bounds__(256) void k_init_deg(int* __restrict__ dego,
                                                  int* __restrict__ degi) {
    int i = blockIdx.x * 256 + threadIdx.x;
    if (i < NN) { dego[i] = 1; degi[i] = 1; }  // self-loop contributes 1
}

__global__ __launch_bounds__(256) void k_count(const int* __restrict__ src,
                                               const int* __restrict__ dst, int E,
                                               int* __restrict__ dego,
                                               int* __restrict__ degi) {
    int e = blockIdx.x * 256 + threadIdx.x;
    if (e < E) {
        atomicAdd(&dego[src[e]], 1);
        atomicAdd(&degi[dst[e]], 1);
    }
}

__global__ __launch_bounds__(256) void k_norm(const int* __restrict__ dego,
                                              const int* __restrict__ degi,
                                              float* __restrict__ ns,
                                              float* __restrict__ nd) {
    int i = blockIdx.x * 256 + threadIdx.x;
    if (i < NN) {
        ns[i] = rsqrtf((float)dego[i]);
        nd[i] = rsqrtf((float)degi[i]);
    }
}

// ---------------- CSR build (scan by dst) ----------------
__device__ __forceinline__ int block_scan_inc(int v, int* sm) {
    int t = threadIdx.x;
    sm[t] = v;
    __syncthreads();
    for (int o = 1; o < SCAN_BLK; o <<= 1) {
        int x = (t >= o) ? sm[t - o] : 0;
        __syncthreads();
        sm[t] += x;
        __syncthreads();
    }
    return sm[t];
}

__global__ __launch_bounds__(SCAN_BLK) void k_scan1(const int* __restrict__ degi,
                                                    int* __restrict__ partials) {
    __shared__ int sm[SCAN_BLK];
    int i = blockIdx.x * SCAN_BLK + threadIdx.x;
    int v = (i < NN) ? (degi[i] - 1) : 0;  // real in-edges only
    block_scan_inc(v, sm);
    if (threadIdx.x == 0) partials[blockIdx.x] = sm[SCAN_BLK - 1];
}

__global__ __launch_bounds__(128) void k_scan2(int* __restrict__ partials, int nb) {
    __shared__ int sm[128];
    int t = threadIdx.x;
    int v = (t < nb) ? partials[t] : 0;
    sm[t] = v;
    __syncthreads();
    for (int o = 1; o < 128; o <<= 1) {
        int x = (t >= o) ? sm[t - o] : 0;
        __syncthreads();
        sm[t] += x;
        __syncthreads();
    }
    if (t < nb) partials[t] = sm[t] - v;  // exclusive
}

__global__ __launch_bounds__(SCAN_BLK) void k_scan3(const int* __restrict__ degi,
                                                    const int* __restrict__ partials,
                                                    int* __restrict__ rowptr,
                                                    int* __restrict__ cursor) {
    __shared__ int sm[SCAN_BLK];
    int i = blockIdx.x * SCAN_BLK + threadIdx.x;
    int v = (i < NN) ? (degi[i] - 1) : 0;
    int incl = block_scan_inc(v, sm);
    int excl = partials[blockIdx.x] + incl - v;
    if (i <= NN) rowptr[i] = excl;   // rowptr[NN] = E
    if (i < NN) cursor[i] = excl;
}

__global__ __launch_bounds__(256) void k_fill(const int* __restrict__ src,
                                              const int* __restrict__ dst, int E,
                                              int* __restrict__ cursor,
                                              int* __restrict__ eidx) {
    int e = blockIdx.x * 256 + threadIdx.x;
    if (e < E) {
        int d = dst[e];
        int p = atomicAdd(&cursor[d], 1);
        eidx[p] = src[e];
    }
}

// Wt[n][k] = bf16(W[k][n])  (transposed so GEMM B-frags read k-contiguous)
__global__ __launch_bounds__(256) void k_convW(const float* __restrict__ W,
                                               ushort* __restrict__ Wt) {
    int n = blockIdx.x, k = threadIdx.x;
    Wt[n * DD + k] = f2bf(W[(size_t)k * DD + n]);
}

// ---------------- MFMA GEMM: H = A @ Wt^T, single column pass ----------------
// Tile 128x256 (A read once), BK=64, 512 threads (8 waves, 2x4 grid), wave
// tile 64x64 (4x4 frags of 16x16x32). ONLY A goes through LDS (dbuf 32 KB);
// B-fragments are read straight from global: Wt is 128 KB = L2-resident per
// XCD, and each bfx8 wave-load is 16 rows x 64 B = 16 fully-consumed cache
// lines (optimal request count). launch_bounds(512,4) caps VGPR at 128 ->
// 2 blocks/CU (16 waves/CU) vs round-6's 1 block/CU at 128 KB LDS.
template <bool FP32A>
__global__ __launch_bounds__(512, 4) void k_mfgemm(const void* __restrict__ Av,
                                                   const float* __restrict__ nrm,
                                                   const ushort* __restrict__ Wt,
                                                   ushort* __restrict__ H) {
    __shared__ uint4 atq[2][128 * 8];  // A tile [128 r][8 chunks of 16B], dbuf
    int t = threadIdx.x;
    int brow = blockIdx.x * 128;
    int lane = t & 63, w = t >> 6;
    int wr = w >> 2, wc = w & 3;       // wave grid 2x4
    int lg = lane >> 4, lr = lane & 15;

    // A staging: 1024 chunks/tile, 2 per thread (rows t>>3 and 64+(t>>3))
    int sr = t >> 3, sc = t & 7;
    int rows_[2];
    float ns_[2];
#pragma unroll
    for (int i = 0; i < 2; ++i) {
        int r = brow + sr + i * 64;
        if (r >= NN) r = NN - 1;  // tail clamp (results discarded on store)
        rows_[i] = r;
        if (FP32A) ns_[i] = nrm[r];
    }

    // B base pointers: lane-row lr of each ni-fragment, k-offset folds to imm
    const uint4* wb[4];
#pragma unroll
    for (int ni = 0; ni < 4; ++ni)
        wb[ni] = (const uint4*)(Wt + (size_t)(wc * 64 + ni * 16 + lr) * DD);

    fx4 acc[4][4];
#pragma unroll
    for (int mi = 0; mi < 4; ++mi)
#pragma unroll
        for (int ni = 0; ni < 4; ++ni)
            acc[mi][ni] = (fx4){0.f, 0.f, 0.f, 0.f};

    uint4 sva[2];
    float4 svf[2][2];

    auto ldA = [&](int ks) {
        if (FP32A) {
            const float* X = (const float*)Av;
#pragma unroll
            for (int i = 0; i < 2; ++i) {
                const float4* p =
                    (const float4*)(X + (size_t)rows_[i] * DD + ks * 64 + sc * 8);
                svf[i][0] = p[0];
                svf[i][1] = p[1];
            }
        } else {
            const ushort* A = (const ushort*)Av;
#pragma unroll
            for (int i = 0; i < 2; ++i)
                sva[i] = *(const uint4*)(A + (size_t)rows_[i] * DD + ks * 64 + sc * 8);
        }
    };
    auto wrA = [&](int buf) {
#pragma unroll
        for (int i = 0; i < 2; ++i) {
            int r = sr + i * 64;
            uint4 u;
            if (FP32A) {
                float s = ns_[i];
                float4 a = svf[i][0], b = svf[i][1];
                u.x = (uint)f2bf(a.x * s) | ((uint)f2bf(a.y * s) << 16);
                u.y = (uint)f2bf(a.z * s) | ((uint)f2bf(a.w * s) << 16);
                u.z = (uint)f2bf(b.x * s) | ((uint)f2bf(b.y * s) << 16);
                u.w = (uint)f2bf(b.z * s) | ((uint)f2bf(b.w * s) << 16);
            } else {
                u = sva[i];
            }
            atq[buf][r * 8 + (sc ^ (r & 7))] = u;
        }
    };

    ldA(0);
    wrA(0);
    __syncthreads();

    int buf = 0;
#pragma unroll
    for (int ks = 0; ks < 4; ++ks) {
        if (ks < 3) ldA(ks + 1);  // issue next A chunk early
#pragma unroll
        for (int kk = 0; kk < 2; ++kk) {
            bfx8 bfr[4], af[4];
#pragma unroll
            for (int ni = 0; ni < 4; ++ni)  // global (L2-hit) B loads first
                bfr[ni] = *(const bfx8*)&wb[ni][ks * 8 + kk * 4 + lg];
#pragma unroll
            for (int mi = 0; mi < 4; ++mi) {
                int r = wr * 64 + mi * 16 + lr;
                int c = kk * 4 + lg;
                af[mi] = *(const bfx8*)&atq[buf][r * 8 + (c ^ (r & 7))];
            }
#pragma unroll
            for (int mi = 0; mi < 4; ++mi)
#pragma unroll
                for (int ni = 0; ni < 4; ++ni)
                    acc[mi][ni] = __builtin_amdgcn_mfma_f32_16x16x32_bf16(
                        af[mi], bfr[ni], acc[mi][ni], 0, 0, 0);
        }
        if (ks < 3) wrA(buf ^ 1);  // write late, into the other buffer
        __syncthreads();
        buf ^= 1;
    }

    // epilogue: C/D layout col=lane&15, row=(lane>>4)*4+reg (verified m89/m91)
#pragma unroll
    for (int mi = 0; mi < 4; ++mi) {
        int rbase = brow + wr * 64 + mi * 16 + lg * 4;
#pragma unroll
        for (int ni = 0; ni < 4; ++ni) {
            int col = wc * 64 + ni * 16 + lr;
#pragma unroll
            for (int j = 0; j < 4; ++j) {
                int row = rbase + j;
                if (row < NN) H[(size_t)row * DD + col] = f2bf(acc[mi][ni][j]);
            }
        }
    }
}

// ---------------- SpMM (bf16 gather, fp32 accum): one wave per dst node ----
// layer1: obf = bf16(relu(agg*nd + b) * ns)   (pre-scaled next-GEMM input)
// layer2: of  = agg*nd + b (final fp32, nontemporal store: write-once data,
//               keep it from evicting the gather working set)
__global__ __launch_bounds__(256) void k_spmm_bf(const ushort* __restrict__ T,
                                                 const int* __restrict__ rowptr,
                                                 const int* __restrict__ eidx,
                                                 const float* __restrict__ nd,
                                                 const float* __restrict__ ns,
                                                 const float* __restrict__ bias,
                                                 ushort* __restrict__ obf,
                                                 float* __restrict__ of,
                                                 int layer1) {
    int wid = threadIdx.x >> 6, lane = threadIdx.x & 63;
    int node = blockIdx.x * 4 + wid;
    if (node >= NN) return;
    int c = lane << 2;  // 4 bf16 per lane
    uint2 sv = *(const uint2*)(T + (size_t)node * DD + c);  // self-loop
    float p0[4], p1[4], p2[4], p3[4];
    p0[0] = __uint_as_float(sv.x << 16);
    p0[1] = __uint_as_float(sv.x & 0xffff0000u);
    p0[2] = __uint_as_float(sv.y << 16);
    p0[3] = __uint_as_float(sv.y & 0xffff0000u);
#pragma unroll
    for (int j = 0; j < 4; ++j) { p1[j] = 0.f; p2[j] = 0.f; p3[j] = 0.f; }
    int e = rowptr[node], end = rowptr[node + 1];
    for (; e + 3 < end; e += 4) {
        int s0 = eidx[e], s1 = eidx[e + 1], s2 = eidx[e + 2], s3 = eidx[e + 3];
        uint2 v0 = *(const uint2*)(T + (size_t)s0 * DD + c);
        uint2 v1 = *(const uint2*)(T + (size_t)s1 * DD + c);
        uint2 v2 = *(const uint2*)(T + (size_t)s2 * DD + c);
        uint2 v3 = *(const uint2*)(T + (size_t)s3 * DD + c);
        p0[0] += __uint_as_float(v0.x << 16);
        p0[1] += __uint_as_float(v0.x & 0xffff0000u);
        p0[2] += __uint_as_float(v0.y << 16);
        p0[3] += __uint_as_float(v0.y & 0xffff0000u);
        p1[0] += __uint_as_float(v1.x << 16);
        p1[1] += __uint_as_float(v1.x & 0xffff0000u);
        p1[2] += __uint_as_float(v1.y << 16);
        p1[3] += __uint_as_float(v1.y & 0xffff0000u);
        p2[0] += __uint_as_float(v2.x << 16);
        p2[1] += __uint_as_float(v2.x & 0xffff0000u);
        p2[2] += __uint_as_float(v2.y << 16);
        p2[3] += __uint_as_float(v2.y & 0xffff0000u);
        p3[0] += __uint_as_float(v3.x << 16);
        p3[1] += __uint_as_float(v3.x & 0xffff0000u);
        p3[2] += __uint_as_float(v3.y << 16);
        p3[3] += __uint_as_float(v3.y & 0xffff0000u);
    }
    for (; e < end; ++e) {
        int s0 = eidx[e];
        uint2 v0 = *(const uint2*)(T + (size_t)s0 * DD + c);
        p0[0] += __uint_as_float(v0.x << 16);
        p0[1] += __uint_as_float(v0.x & 0xffff0000u);
        p0[2] += __uint_as_float(v0.y << 16);
        p0[3] += __uint_as_float(v0.y & 0xffff0000u);
    }
#pragma unroll
    for (int j = 0; j < 4; ++j) p0[j] += (p1[j] + p2[j]) + p3[j];
    float n = nd[node];
    float4 bb = *(const float4*)(bias + c);
    float o0 = fmaf(p0[0], n, bb.x);
    float o1 = fmaf(p0[1], n, bb.y);
    float o2 = fmaf(p0[2], n, bb.z);
    float o3 = fmaf(p0[3], n, bb.w);
    if (layer1) {
        float s = ns[node];
        o0 = fmaxf(o0, 0.f) * s; o1 = fmaxf(o1, 0.f) * s;
        o2 = fmaxf(o2, 0.f) * s; o3 = fmaxf(o3, 0.f) * s;
        uint lo = (uint)f2bf(o0) | ((uint)f2bf(o1) << 16);
        uint hi = (uint)f2bf(o2) | ((uint)f2bf(o3) << 16);
        *(uint2*)(obf + (size_t)node * DD + c) = make_uint2(lo, hi);
    } else {
        fx4 o = {o0, o1, o2, o3};
        __builtin_nontemporal_store(o, (fx4*)(of + (size_t)node * DD + c));
    }
}

extern "C" void kernel_launch(void* const* d_in, const int* in_sizes, int n_in,
                              void* d_out, int out_size, void* d_ws, size_t ws_size,
                              hipStream_t stream) {
    const float* features = (const float*)d_in[0];
    const int* src = (const int*)d_in[1];
    const int* dst = (const int*)d_in[2];
    const float* W1 = (const float*)d_in[3];
    const float* b1 = (const float*)d_in[4];
    const float* W2 = (const float*)d_in[5];
    const float* b2 = (const float*)d_in[6];
    int E = in_sizes[1];
    float* out = (float*)d_out;

    size_t off = 0;
    auto alloc = [&](size_t nbytes) -> void* {
        void* p = (char*)d_ws + off;
        off += (nbytes + 255) & ~(size_t)255;
        return p;
    };
    int* dego = (int*)alloc((size_t)NN * 4);
    int* degi = (int*)alloc((size_t)NN * 4);
    float* norm_src = (float*)alloc((size_t)NN * 4);
    float* norm_dst = (float*)alloc((size_t)NN * 4);
    int* rowptr = (int*)alloc((size_t)(NN + 1) * 4);
    int* cursor = (int*)alloc((size_t)NN * 4);
    int* partials = (int*)alloc(128 * 4);
    int* eidx = (int*)alloc((size_t)E * 4);
    ushort* Wt1 = (ushort*)alloc((size_t)DD * DD * 2);
    ushort* Wt2 = (ushort*)alloc((size_t)DD * DD * 2);
    ushort* Xbf = (ushort*)alloc((size_t)NN * DD * 2);
    ushort* Hbf = (ushort*)alloc((size_t)NN * DD * 2);

    const int NB = (NN + SCAN_BLK - 1) / SCAN_BLK;  // 98

    k_init_deg<<<(NN + 255) / 256, 256, 0, stream>>>(dego, degi);
    k_count<<<(E + 255) / 256, 256, 0, stream>>>(src, dst, E, dego, degi);
    k_norm<<<(NN + 255) / 256, 256, 0, stream>>>(dego, degi, norm_src, norm_dst);
    k_scan1<<<NB, SCAN_BLK, 0, stream>>>(degi, partials);
    k_scan2<<<1, 128, 0, stream>>>(partials, NB);
    k_scan3<<<NB, SCAN_BLK, 0, stream>>>(degi, partials, rowptr, cursor);
    k_fill<<<(E + 255) / 256, 256, 0, stream>>>(src, dst, E, cursor, eidx);

    k_convW<<<DD, DD, 0, stream>>>(W1, Wt1);
    k_convW<<<DD, DD, 0, stream>>>(W2, Wt2);

    dim3 ggrid((NN + 127) / 128);  // 782, single column pass (BN=256)
    // layer 1 (GEMM reads fp32 features, scales by norm_src while staging)
    k_mfgemm<true><<<ggrid, 512, 0, stream>>>(features, norm_src, Wt1, Hbf);
    k_spmm_bf<<<(NN + 3) / 4, 256, 0, stream>>>(Hbf, rowptr, eidx, norm_dst,
                                                norm_src, b1, Xbf, out, 1);
    // layer 2
    k_mfgemm<false><<<ggrid, 512, 0, stream>>>(Xbf, nullptr, Wt2, Hbf);
    k_spmm_bf<<<(NN + 3) / 4, 256, 0, stream>>>(Hbf, rowptr, eidx, norm_dst,
                                                norm_src, b2, nullptr, out, 0);
}